// Round 5
// baseline (193.305 us; speedup 1.0000x reference)
//
#include <hip/hip_runtime.h>

typedef __bf16 bf16;
typedef bf16 bf16x8 __attribute__((ext_vector_type(8)));
typedef bf16 bf16x4 __attribute__((ext_vector_type(4)));
typedef float f32x4 __attribute__((ext_vector_type(4)));

#define SEQ 256
#define DH  32

// LDS arena offsets (bytes). Row strides: 40 bf16 (80B) and 264 bf16 (528B)
// are 16B multiples; all hot read/write patterns verified <=2-way on banks.
#define KC_OFF 0        // Kc [256][40] bf16 = 20480
#define VT_OFF 20480    // Vt [32][264] bf16 = 16896
#define TC_OFF 37376    // Tc [256][40] bf16 = 20480 (Q during staging, then tri chunks)
#define PB_OFF 57856    // Pb [8][32][40] bf16 = 20480 (wave-private P rows)
#define MC_OFF 78336    // Mc [256] f32 = 1024
#define ARENA_BYTES 79360   // 77.5 KB -> 2 blocks/CU

// One block per (n,h): 512 threads = 8 waves, wave owns 32 queries.
// All scattered access lives in LDS; global reads are dense 128B-contiguous
// streams. tri chunk c+1 is register-carried across chunk c's compute.
__global__ __launch_bounds__(512, 4) void attn_mfma5_kernel(
    const float* __restrict__ q,
    const float* __restrict__ k,
    const float* __restrict__ v,
    const float* __restrict__ mask_bias,   // [N][SEQ]
    const float* __restrict__ tri_bias,    // [H][SEQ][SEQ]
    float* __restrict__ out)
{
    __shared__ __align__(16) char arena[ARENA_BYTES];
    bf16*  Kc = (bf16*)(arena + KC_OFF);
    bf16*  Vt = (bf16*)(arena + VT_OFF);
    bf16*  Tc = (bf16*)(arena + TC_OFF);
    bf16*  Pb = (bf16*)(arena + PB_OFF);
    float* Mc = (float*)(arena + MC_OFF);
    float* Ob = (float*)arena;             // epilogue overlay [256][36] f32 = 36864B

    const int tid  = threadIdx.x;
    const int wave = tid >> 6;
    const int lane = tid & 63;
    const int l15  = lane & 15;
    const int quad = lane >> 4;

    // XCD-aware decode: h fixed per XCD -> 1MB tri slice stays L2-resident.
    const int b   = blockIdx.x;            // 0..1023
    const int xcd = b & 7;
    const int h   = xcd & 3;
    const int n   = (b >> 3) + ((xcd >> 2) << 7);
    const int inst = n * 4 + h;

    const float* qb = q + (size_t)inst * SEQ * DH;
    const float* kb = k + (size_t)inst * SEQ * DH;
    const float* vb = v + (size_t)inst * SEQ * DH;
    const float* mb = mask_bias + (size_t)n * SEQ;
    const float* tb = tri_bias + (size_t)h * SEQ * SEQ;
    float*       ob = out + (size_t)inst * SEQ * DH;

    const float K1    = 0.17677669529663687f * 1.44269504088896f; // sm_scale*log2e
    const float LOG2E = 1.44269504088896f;
    const f32x4 zero4 = {0.f, 0.f, 0.f, 0.f};

    // ---- tri staging geometry: thread pair (2 per row) covers 64B each ----
    const int   ts   = tid >> 1;            // tri row this thread stages
    const int   tcb  = (tid & 1) * 16;      // col base within 32-col chunk
    const float* trow = tb + (size_t)ts * SEQ + tcb;
    bf16* tdst = &Tc[ts * 40 + tcb];

    // (A) issue tri chunk-0 loads (dense 64B-per-thread streams)
    float4 TR0 = *(const float4*)(trow + 0);
    float4 TR1 = *(const float4*)(trow + 4);
    float4 TR2 = *(const float4*)(trow + 8);
    float4 TR3 = *(const float4*)(trow + 12);

    // (B) stage Q->Tc, K->Kc (bf16, stride 40), V^T->Vt, mask->Mc; coalesced
    #pragma unroll
    for (int i = 0; i < 4; ++i) {
        int p  = i * 512 + tid;            // float4 piece: row = p>>3, d4 = (p&7)*4
        int s  = p >> 3;
        int d4 = (p & 7) * 4;
        float4 fq = ((const float4*)qb)[p];
        float4 fk = ((const float4*)kb)[p];
        float4 fv = ((const float4*)vb)[p];
        bf16x4 q4; q4[0]=(bf16)fq.x; q4[1]=(bf16)fq.y; q4[2]=(bf16)fq.z; q4[3]=(bf16)fq.w;
        *(bf16x4*)&Tc[s * 40 + d4] = q4;
        bf16x4 k4; k4[0]=(bf16)fk.x; k4[1]=(bf16)fk.y; k4[2]=(bf16)fk.z; k4[3]=(bf16)fk.w;
        *(bf16x4*)&Kc[s * 40 + d4] = k4;
        Vt[(d4 + 0) * 264 + s] = (bf16)fv.x;
        Vt[(d4 + 1) * 264 + s] = (bf16)fv.y;
        Vt[(d4 + 2) * 264 + s] = (bf16)fv.z;
        Vt[(d4 + 3) * 264 + s] = (bf16)fv.w;
    }
    if (tid < SEQ) Mc[tid] = mb[tid];
    __syncthreads();

    // (C) Q b-frags from Tc (wave w owns queries w*32..w*32+31)
    bf16x8 qfrag[2];
    qfrag[0] = *(const bf16x8*)&Tc[(wave * 32 + l15) * 40 + quad * 8];
    qfrag[1] = *(const bf16x8*)&Tc[(wave * 32 + 16 + l15) * 40 + quad * 8];
    __syncthreads();                       // Tc now free for tri

    // (D) tri chunk 0 -> Tc
    {
        bf16x4 x;
        x[0]=(bf16)TR0.x; x[1]=(bf16)TR0.y; x[2]=(bf16)TR0.z; x[3]=(bf16)TR0.w; *(bf16x4*)(tdst + 0)  = x;
        x[0]=(bf16)TR1.x; x[1]=(bf16)TR1.y; x[2]=(bf16)TR1.z; x[3]=(bf16)TR1.w; *(bf16x4*)(tdst + 4)  = x;
        x[0]=(bf16)TR2.x; x[1]=(bf16)TR2.y; x[2]=(bf16)TR2.z; x[3]=(bf16)TR2.w; *(bf16x4*)(tdst + 8)  = x;
        x[0]=(bf16)TR3.x; x[1]=(bf16)TR3.y; x[2]=(bf16)TR3.z; x[3]=(bf16)TR3.w; *(bf16x4*)(tdst + 12) = x;
    }
    __syncthreads();

    f32x4 oacc[2][2];
    #pragma unroll
    for (int st = 0; st < 2; ++st)
        #pragma unroll
        for (int dt = 0; dt < 2; ++dt)
            oacc[st][dt] = zero4;
    float lpart[2] = {0.f, 0.f};

    // ---- main loop: 8 chunks of 32 keys ----
    for (int c = 0; c < 8; ++c) {
        // issue next chunk's tri loads (consumed after the compute below)
        if (c < 7) {
            const float* tp = trow + (c + 1) * 32;
            TR0 = *(const float4*)(tp + 0);
            TR1 = *(const float4*)(tp + 4);
            TR2 = *(const float4*)(tp + 8);
            TR3 = *(const float4*)(tp + 12);
        }

        // ---- compute chunk c: QK + bias + exp -> Pb, then PV ----
        #pragma unroll
        for (int half = 0; half < 2; ++half) {
            bf16x8 kfrag = *(const bf16x8*)&Kc[(c * 32 + half * 16 + l15) * 40 + quad * 8];
            float4 mk = *(const float4*)&Mc[c * 32 + half * 16 + quad * 4];
            float mkl0 = mk.x * LOG2E, mkl1 = mk.y * LOG2E;
            float mkl2 = mk.z * LOG2E, mkl3 = mk.w * LOG2E;

            #pragma unroll
            for (int st = 0; st < 2; ++st) {
                const int srow = wave * 32 + st * 16 + l15;
                bf16x4 t4 = *(const bf16x4*)&Tc[srow * 40 + half * 16 + quad * 4];
                f32x4 cf = __builtin_amdgcn_mfma_f32_16x16x32_bf16(kfrag, qfrag[st], zero4, 0, 0, 0);
                float e0 = __builtin_amdgcn_exp2f(fmaf(cf[0], K1, fmaf((float)t4[0], LOG2E, mkl0)));
                float e1 = __builtin_amdgcn_exp2f(fmaf(cf[1], K1, fmaf((float)t4[1], LOG2E, mkl1)));
                float e2 = __builtin_amdgcn_exp2f(fmaf(cf[2], K1, fmaf((float)t4[2], LOG2E, mkl2)));
                float e3 = __builtin_amdgcn_exp2f(fmaf(cf[3], K1, fmaf((float)t4[3], LOG2E, mkl3)));
                lpart[st] += (e0 + e1) + (e2 + e3);
                bf16x4 pk; pk[0]=(bf16)e0; pk[1]=(bf16)e1; pk[2]=(bf16)e2; pk[3]=(bf16)e3;
                *(bf16x4*)&Pb[(wave * 32 + st * 16 + l15) * 40 + half * 16 + quad * 4] = pk;
            }
        }

        // PV over this chunk (Pb rows wave-private: no barrier needed)
        {
            bf16x8 vf0 = *(const bf16x8*)&Vt[(l15) * 264 + c * 32 + quad * 8];
            bf16x8 vf1 = *(const bf16x8*)&Vt[(16 + l15) * 264 + c * 32 + quad * 8];
            #pragma unroll
            for (int st = 0; st < 2; ++st) {
                bf16x8 pf = *(const bf16x8*)&Pb[(wave * 32 + st * 16 + l15) * 40 + quad * 8];
                oacc[st][0] = __builtin_amdgcn_mfma_f32_16x16x32_bf16(pf, vf0, oacc[st][0], 0, 0, 0);
                oacc[st][1] = __builtin_amdgcn_mfma_f32_16x16x32_bf16(pf, vf1, oacc[st][1], 0, 0, 0);
            }
        }

        __syncthreads();                   // all waves done reading Tc chunk c
        if (c < 7) {
            bf16x4 x;
            x[0]=(bf16)TR0.x; x[1]=(bf16)TR0.y; x[2]=(bf16)TR0.z; x[3]=(bf16)TR0.w; *(bf16x4*)(tdst + 0)  = x;
            x[0]=(bf16)TR1.x; x[1]=(bf16)TR1.y; x[2]=(bf16)TR1.z; x[3]=(bf16)TR1.w; *(bf16x4*)(tdst + 4)  = x;
            x[0]=(bf16)TR2.x; x[1]=(bf16)TR2.y; x[2]=(bf16)TR2.z; x[3]=(bf16)TR2.w; *(bf16x4*)(tdst + 8)  = x;
            x[0]=(bf16)TR3.x; x[1]=(bf16)TR3.y; x[2]=(bf16)TR3.z; x[3]=(bf16)TR3.w; *(bf16x4*)(tdst + 12) = x;
        }
        __syncthreads();                   // tri chunk c+1 visible
    }

    // ---- softmax denominators ----
    float linv[2];
    #pragma unroll
    for (int st = 0; st < 2; ++st) {
        float x = lpart[st];
        x += __shfl_xor(x, 16);
        x += __shfl_xor(x, 32);
        linv[st] = 1.0f / x;               // row l15 of tile st (all quads hold it)
    }

    // ---- epilogue: bounce through LDS overlay for coalesced stores ----
    // (last barrier above already separates loop reads from the overlay)
    #pragma unroll
    for (int st = 0; st < 2; ++st) {
        #pragma unroll
        for (int r = 0; r < 4; ++r) {
            float invr = __shfl(linv[st], quad * 4 + r);
            int s = wave * 32 + st * 16 + quad * 4 + r;
            Ob[s * 36 + l15]      = oacc[st][0][r] * invr;
            Ob[s * 36 + 16 + l15] = oacc[st][1][r] * invr;
        }
    }
    __syncthreads();

    #pragma unroll
    for (int i = 0; i < 4; ++i) {
        int p  = i * 512 + tid;
        int s  = p >> 3;
        int d4 = (p & 7) * 4;
        f32x4 o = *(const f32x4*)&Ob[s * 36 + d4];
        float4 w; w.x = o[0]; w.y = o[1]; w.z = o[2]; w.w = o[3];
        ((float4*)ob)[p] = w;
    }
}

extern "C" void kernel_launch(void* const* d_in, const int* in_sizes, int n_in,
                              void* d_out, int out_size, void* d_ws, size_t ws_size,
                              hipStream_t stream) {
    const float* q    = (const float*)d_in[0];
    const float* k    = (const float*)d_in[1];
    const float* v    = (const float*)d_in[2];
    const float* mask = (const float*)d_in[3];
    const float* tri  = (const float*)d_in[4];
    float* out = (float*)d_out;

    attn_mfma5_kernel<<<dim3(1024), dim3(512), 0, stream>>>(q, k, v, mask, tri, out);
}